// Round 7
// baseline (475.236 us; speedup 1.0000x reference)
//
#include <hip/hip_runtime.h>
#include <hip/hip_bf16.h>

#define NTOK   256
#define DMODEL 512
#define NHEAD  8
#define HD     64
#define HALF   32
#define FF     1536
#define RCFF   2048
#define VOCAB  32000
#define NLAYER 2
#define NSTEPS 4
#define EPSV   1e-6f
#define THR    0.99f

typedef __attribute__((ext_vector_type(8))) short bf16x8;
typedef __attribute__((ext_vector_type(4))) float f32x4;

// ---------------- embedding gather ----------------
__global__ void k_embed(const int* __restrict__ ids, const float* __restrict__ emb,
                        float* __restrict__ x) {
    int row = blockIdx.x;
    int id = ids[row];
    for (int d = threadIdx.x; d < DMODEL; d += blockDim.x)
        x[row * DMODEL + d] = emb[(size_t)id * DMODEL + d];
}

// ---------------- rmsnorm (one block per row) ----------------
__global__ __launch_bounds__(256) void k_rmsnorm(const float* __restrict__ in,
                                                 const float* __restrict__ w,
                                                 float* __restrict__ out) {
    int row = blockIdx.x;
    const float* xr = in + (size_t)row * DMODEL;
    float s = 0.f;
    for (int d = threadIdx.x; d < DMODEL; d += 256) { float v = xr[d]; s += v * v; }
    __shared__ float red[4];
    int lane = threadIdx.x & 63, wv = threadIdx.x >> 6;
    for (int o = 32; o > 0; o >>= 1) s += __shfl_xor(s, o);
    if (lane == 0) red[wv] = s;
    __syncthreads();
    float tot = red[0] + red[1] + red[2] + red[3];
    float scale = rsqrtf(tot * (1.f / DMODEL) + EPSV);
    for (int d = threadIdx.x; d < DMODEL; d += 256)
        out[(size_t)row * DMODEL + d] = xr[d] * scale * w[d];
}

// ---------------- split-K matmul partial, 128x64 tile, 8x4 acc ----------------
// A-fragment LDS reads are 4-address broadcast (free); FMA-bound inner loop.
__global__ __launch_bounds__(256) void k_mm_part2(const float* __restrict__ A,
                                                  const float* __restrict__ W,
                                                  float* __restrict__ Cp,
                                                  int K, int N, int kc) {
    __shared__ float As[16][132];
    __shared__ float Ws[16][68];
    const int bn = blockIdx.x * 64;
    const int bm = blockIdx.y * 128;
    const int kz = blockIdx.z * kc;
    const int tx = threadIdx.x & 15;   // 4-col group
    const int ty = threadIdx.x >> 4;   // 8-row group
    float acc[8][4] = {};
    for (int k0 = kz; k0 < kz + kc; k0 += 16) {
#pragma unroll
        for (int r = 0; r < 2; ++r) {
            int f = threadIdx.x + r * 256;           // 512 float4 of A tile
            int row = f >> 2, kq = (f & 3) * 4;
            float4 v = *(const float4*)&A[(size_t)(bm + row) * K + k0 + kq];
            As[kq + 0][row] = v.x;
            As[kq + 1][row] = v.y;
            As[kq + 2][row] = v.z;
            As[kq + 3][row] = v.w;
        }
        {
            int kw = threadIdx.x >> 4, n4 = (threadIdx.x & 15) * 4;
            *(float4*)&Ws[kw][n4] = *(const float4*)&W[(size_t)(k0 + kw) * N + bn + n4];
        }
        __syncthreads();
#pragma unroll
        for (int kk = 0; kk < 16; ++kk) {
            float4 a0 = *(const float4*)&As[kk][ty * 8];
            float4 a1 = *(const float4*)&As[kk][ty * 8 + 4];
            float4 bv = *(const float4*)&Ws[kk][tx * 4];
            float a[8] = {a0.x, a0.y, a0.z, a0.w, a1.x, a1.y, a1.z, a1.w};
            float b[4] = {bv.x, bv.y, bv.z, bv.w};
#pragma unroll
            for (int i = 0; i < 8; ++i)
#pragma unroll
                for (int j = 0; j < 4; ++j)
                    acc[i][j] = fmaf(a[i], b[j], acc[i][j]);
        }
        __syncthreads();
    }
    float* cp = Cp + (size_t)blockIdx.z * (size_t)(gridDim.y * 128) * N;
#pragma unroll
    for (int i = 0; i < 8; ++i) {
        int m = bm + ty * 8 + i;
#pragma unroll
        for (int j = 0; j < 4; ++j)
            cp[(size_t)m * N + bn + tx * 4 + j] = acc[i][j];
    }
}

// ---------------- gate+up combined split-K partial (one launch) ----------------
// z = 0..7: z>>2 selects gate(0)/up(1); z&3 selects the 128-wide k chunk.
__global__ __launch_bounds__(256) void k_gu_part2(const float* __restrict__ A,
                                                  const float* __restrict__ Wg,
                                                  const float* __restrict__ Wu,
                                                  float* __restrict__ GU) {
    __shared__ float As[16][132];
    __shared__ float Ws[16][68];
    const int bn = blockIdx.x * 64;
    const int bm = blockIdx.y * 128;
    const int z = blockIdx.z;
    const float* W = (z >> 2) ? Wu : Wg;
    const int kz = (z & 3) * 128;
    const int tx = threadIdx.x & 15;
    const int ty = threadIdx.x >> 4;
    float acc[8][4] = {};
    for (int k0 = kz; k0 < kz + 128; k0 += 16) {
#pragma unroll
        for (int r = 0; r < 2; ++r) {
            int f = threadIdx.x + r * 256;
            int row = f >> 2, kq = (f & 3) * 4;
            float4 v = *(const float4*)&A[(size_t)(bm + row) * DMODEL + k0 + kq];
            As[kq + 0][row] = v.x;
            As[kq + 1][row] = v.y;
            As[kq + 2][row] = v.z;
            As[kq + 3][row] = v.w;
        }
        {
            int kw = threadIdx.x >> 4, n4 = (threadIdx.x & 15) * 4;
            *(float4*)&Ws[kw][n4] = *(const float4*)&W[(size_t)(k0 + kw) * FF + bn + n4];
        }
        __syncthreads();
#pragma unroll
        for (int kk = 0; kk < 16; ++kk) {
            float4 a0 = *(const float4*)&As[kk][ty * 8];
            float4 a1 = *(const float4*)&As[kk][ty * 8 + 4];
            float4 bv = *(const float4*)&Ws[kk][tx * 4];
            float a[8] = {a0.x, a0.y, a0.z, a0.w, a1.x, a1.y, a1.z, a1.w};
            float b[4] = {bv.x, bv.y, bv.z, bv.w};
#pragma unroll
            for (int i = 0; i < 8; ++i)
#pragma unroll
                for (int j = 0; j < 4; ++j)
                    acc[i][j] = fmaf(a[i], b[j], acc[i][j]);
        }
        __syncthreads();
    }
    float* cp = GU + (size_t)z * (NTOK * FF);
#pragma unroll
    for (int i = 0; i < 8; ++i) {
        int m = bm + ty * 8 + i;
#pragma unroll
        for (int j = 0; j < 4; ++j)
            cp[(size_t)m * FF + bn + tx * 4 + j] = acc[i][j];
    }
}

// ---------------- split-K elementwise reduce (+optional gelu) ----------------
__global__ void k_mm_finish(const float* __restrict__ Cp, const float* __restrict__ res,
                            float* __restrict__ C, int tot, int zstride, int nz, int act) {
    int i = blockIdx.x * 256 + threadIdx.x;
    if (i >= tot) return;
    float s = 0.f;
    for (int z = 0; z < nz; ++z) s += Cp[(size_t)z * zstride + i];
    if (res) s += res[i];
    if (act == 1) {  // gelu (tanh approx, jax default)
        float xg = s;
        float inner = 0.79788456080286536f * (xg + 0.044715f * xg * xg * xg);
        s = 0.5f * xg * (1.f + tanhf(inner));
    }
    C[i] = s;
}

// ---------------- reduce + silu(g)*u  (gate z=0..3, up z=4..7) ----------------
__global__ void k_finish_silumul(const float* __restrict__ GU, float* __restrict__ C) {
    int i = blockIdx.x * 256 + threadIdx.x;   // tot = 256*1536
    float g = 0.f, u = 0.f;
#pragma unroll
    for (int z = 0; z < 4; ++z) {
        g += GU[(size_t)z * (NTOK * FF) + i];
        u += GU[(size_t)(z + 4) * (NTOK * FF) + i];
    }
    float sig = 1.f / (1.f + expf(-g));
    C[i] = g * sig * u;
}

// ---------------- reduce + residual + dual write (raw, rmsnorm) ----------------
__global__ __launch_bounds__(256) void k_finish_norm(const float* __restrict__ Cp,
                                                     const float* __restrict__ res,
                                                     const float* __restrict__ normw,
                                                     float* __restrict__ out_raw,
                                                     float* __restrict__ out_norm,
                                                     int nz) {
    int row = blockIdx.x, t = threadIdx.x;
    int c0 = t, c1 = t + 256;
    size_t base = (size_t)row * DMODEL;
    float v0 = 0.f, v1 = 0.f;
    for (int z = 0; z < nz; ++z) {
        size_t zb = (size_t)z * (NTOK * DMODEL) + base;
        v0 += Cp[zb + c0];
        v1 += Cp[zb + c1];
    }
    v0 += res[base + c0];
    v1 += res[base + c1];
    float ss = v0 * v0 + v1 * v1;
    __shared__ float red[4];
    int lane = t & 63, wv = t >> 6;
    for (int o = 32; o > 0; o >>= 1) ss += __shfl_xor(ss, o);
    if (lane == 0) red[wv] = ss;
    __syncthreads();
    float tot = red[0] + red[1] + red[2] + red[3];
    float scale = rsqrtf(tot * (1.f / DMODEL) + EPSV);
    out_raw[base + c0] = v0;
    out_raw[base + c1] = v1;
    out_norm[base + c0] = v0 * scale * normw[c0];
    out_norm[base + c1] = v1 * scale * normw[c1];
}

// ---------------- qkv reduce + RoPE fused (z=4 slices, N=1536) ----------------
__global__ __launch_bounds__(256) void k_qkv_finish_rope(const float* __restrict__ Cp,
                                                         float* __restrict__ qkv) {
    int pos = blockIdx.x, t = threadIdx.x;
    int h = t >> 5, d = t & 31;
    size_t base = (size_t)pos * FF;
    auto S = [&](int col) {
        float s = 0.f;
#pragma unroll
        for (int z = 0; z < 4; ++z) s += Cp[(size_t)z * (NTOK * FF) + base + col];
        return s;
    };
    int cq0 = h * HD + d, cq1 = cq0 + HALF;
    int ck0 = DMODEL + cq0, ck1 = ck0 + HALF;
    int cv0 = 2 * DMODEL + t, cv1 = cv0 + 256;
    float q0 = S(cq0), q1 = S(cq1);
    float k0 = S(ck0), k1 = S(ck1);
    float v0 = S(cv0), v1 = S(cv1);
    float inv = powf(10000.f, -(float)d / 32.f);
    float ang = (float)pos * inv;
    float c = cosf(ang), s = sinf(ang);
    qkv[base + cq0] = q0 * c - q1 * s;
    qkv[base + cq1] = q0 * s + q1 * c;
    qkv[base + ck0] = k0 * c - k1 * s;
    qkv[base + ck1] = k0 * s + k1 * c;
    qkv[base + cv0] = v0;
    qkv[base + cv1] = v1;
}

// ---------------- attention: one block per (head, query) ----------------
__global__ __launch_bounds__(256) void k_attn(const float* __restrict__ qkv,
                                              float* __restrict__ out) {
    int h = blockIdx.x;
    int qi = blockIdx.y;
    int t = threadIdx.x;
    __shared__ float qs[HD];
    __shared__ float ps[NTOK];
    __shared__ float red[4];
    __shared__ float red2[4];
    __shared__ float os[4][HD];
    if (t < HD) qs[t] = qkv[(size_t)qi * FF + h * HD + t];
    __syncthreads();
    float sc = -1e30f;
    if (t <= qi) {
        const float* kr = qkv + (size_t)t * FF + DMODEL + h * HD;
        float s = 0.f;
        for (int d = 0; d < HD; ++d) s = fmaf(qs[d], kr[d], s);
        sc = s * 0.125f;
    }
    float m = sc;
    for (int o = 32; o > 0; o >>= 1) m = fmaxf(m, __shfl_xor(m, o));
    int lane = t & 63, wv = t >> 6;
    if (lane == 0) red[wv] = m;
    __syncthreads();
    m = fmaxf(fmaxf(red[0], red[1]), fmaxf(red[2], red[3]));
    float e = (t <= qi) ? expf(sc - m) : 0.f;
    ps[t] = e;
    float sum = e;
    for (int o = 32; o > 0; o >>= 1) sum += __shfl_xor(sum, o);
    if (lane == 0) red2[wv] = sum;
    __syncthreads();
    sum = red2[0] + red2[1] + red2[2] + red2[3];
    float inv = 1.f / sum;
    int d = t & 63, g = t >> 6;
    float acc = 0.f;
    for (int ki = g; ki <= qi; ki += 4)
        acc = fmaf(ps[ki], qkv[(size_t)ki * FF + 2 * DMODEL + h * HD + d], acc);
    os[g][d] = acc * inv;
    __syncthreads();
    if (t < HD)
        out[(size_t)qi * DMODEL + h * HD + t] = os[0][t] + os[1][t] + os[2][t] + os[3][t];
}

// ---------------- halt dots + ACT combine + A/B build, one block per token ----
__global__ __launch_bounds__(256) void k_haltactab(const float* __restrict__ H,
                                                   const float* __restrict__ wh,
                                                   const float* __restrict__ bptr,
                                                   float* __restrict__ ponder_out,
                                                   float* __restrict__ w_out,
                                                   __hip_bfloat16* __restrict__ A,
                                                   __hip_bfloat16* __restrict__ Bm) {
    int i = blockIdx.x, t = threadIdx.x;
    int lane = t & 63, wv = t >> 6;
    __shared__ float red[4];
    __shared__ float hvals[3];
    __shared__ float hw[4];
    for (int s = 1; s <= 3; ++s) {
        const float* hr = H + ((size_t)s * NTOK + i) * DMODEL;
        float a = hr[t] * wh[t] + hr[t + 256] * wh[t + 256];
        for (int o = 32; o > 0; o >>= 1) a += __shfl_xor(a, o);
        if (lane == 0) red[wv] = a;
        __syncthreads();
        if (t == 0)
            hvals[s - 1] = 1.f / (1.f + expf(-(red[0] + red[1] + red[2] + red[3] + bptr[0])));
        __syncthreads();
    }
    if (t == 0) {
        float p[4] = {0.f, hvals[0], hvals[1], hvals[2]};
        float cum = 0.f, rem = 0.f;
        int nrun = 0;
#pragma unroll
        for (int s = 0; s < 4; ++s) {
            float prev = cum;
            cum += p[s];
            bool running = prev < THR;
            bool use_rem = running && ((cum >= THR) || (s == 3));
            float v = 0.f;
            if (running) {
                v = use_rem ? (1.f - prev) : p[s];
                if (use_rem) rem += (1.f - prev);
                nrun++;
            }
            hw[s] = v;
            w_out[i * 4 + s] = v;
        }
        ponder_out[i] = (float)nrun + rem;
    }
    __syncthreads();
    float w0 = hw[0], w1 = hw[1], w2 = hw[2], w3 = hw[3];
    size_t base = (size_t)i * DMODEL;
#pragma unroll
    for (int r = 0; r < 2; ++r) {
        int d = t + r * 256;
        float h0 = H[base + d];
        float h1 = H[(size_t)(NTOK * DMODEL) + base + d];
        float h2 = H[(size_t)(2 * NTOK * DMODEL) + base + d];
        float h3 = H[(size_t)(3 * NTOK * DMODEL) + base + d];
        float h4 = H[(size_t)(4 * NTOK * DMODEL) + base + d];
        A[base + d]  = __float2bfloat16(w0 * h0 + w1 * h1 + w2 * h2 + w3 * h3);
        Bm[base + d] = __float2bfloat16(w0 * h1 + w1 * h2 + w2 * h3 + w3 * h4);
    }
}

// ---------------- final logits via MFMA: out = A @ Wy + B @ Wd ----------------
// M-split: grid (500, 2); block = 128 rows x 64 cols, 8 waves (2 row-halves of
// 64 x 4 col-groups). LDS 25 KB -> 4 blocks/CU; 1000 blocks. Weight tiles
// re-staged per row-half (L3 absorbs the 2x weight re-read).
__global__ __launch_bounds__(512) void k_logits_mfma(const __hip_bfloat16* __restrict__ Abf,
                                                     const __hip_bfloat16* __restrict__ Bbf,
                                                     const float* __restrict__ Wy,
                                                     const float* __restrict__ Wd,
                                                     float* __restrict__ out) {
    __shared__ short Alds[128 * 32];
    __shared__ short Blds[128 * 32];
    __shared__ short Wys[32 * 70];
    __shared__ short Wds[32 * 70];
    const int tid  = threadIdx.x;
    const int wave = tid >> 6;
    const int lane = tid & 63;
    const int rbase = blockIdx.y * 128;       // row half of the 256 tokens
    const int wrow = (wave & 1) * 64;         // 64-row half within tile
    const int wcol = (wave >> 1) * 16;        // 16-col group within block's 64
    const int cl   = lane & 15;
    const int kg   = lane >> 4;
    const int col  = blockIdx.x * 64 + wcol + cl;

    const int kr = tid >> 4;                  // weight staging: 0..31
    const int c4 = (tid & 15) * 4;
    const int sr = tid >> 2;                  // A/B staging row 0..127
    const int skp = (tid & 3) * 8;

    f32x4 acc[4];
#pragma unroll
    for (int i = 0; i < 4; ++i) acc[i] = (f32x4){0.f, 0.f, 0.f, 0.f};

    const float* gy = Wy + (size_t)kr * VOCAB + blockIdx.x * 64 + c4;
    const float* gd = Wd + (size_t)kr * VOCAB + blockIdx.x * 64 + c4;

    float4 ry = *(const float4*)gy;
    float4 rd = *(const float4*)gd;
    bf16x8 ra = *(const bf16x8*)(Abf + (size_t)(rbase + sr) * DMODEL + skp);
    bf16x8 rb = *(const bf16x8*)(Bbf + (size_t)(rbase + sr) * DMODEL + skp);

    for (int t = 0; t < 16; ++t) {
        __syncthreads();  // previous iteration's fragment reads complete
        {
            short2 a, b;
            a.x = (short)__hip_bfloat16_raw(__float2bfloat16(ry.x)).x;
            a.y = (short)__hip_bfloat16_raw(__float2bfloat16(ry.y)).x;
            b.x = (short)__hip_bfloat16_raw(__float2bfloat16(ry.z)).x;
            b.y = (short)__hip_bfloat16_raw(__float2bfloat16(ry.w)).x;
            *(short2*)&Wys[kr * 70 + c4]     = a;
            *(short2*)&Wys[kr * 70 + c4 + 2] = b;
            a.x = (short)__hip_bfloat16_raw(__float2bfloat16(rd.x)).x;
            a.y = (short)__hip_bfloat16_raw(__float2bfloat16(rd.y)).x;
            b.x = (short)__hip_bfloat16_raw(__float2bfloat16(rd.z)).x;
            b.y = (short)__hip_bfloat16_raw(__float2bfloat16(rd.w)).x;
            *(short2*)&Wds[kr * 70 + c4]     = a;
            *(short2*)&Wds[kr * 70 + c4 + 2] = b;
            *(bf16x8*)&Alds[sr * 32 + skp] = ra;
            *(bf16x8*)&Blds[sr * 32 + skp] = rb;
        }
        if (t < 15) {  // prefetch next 32-k tile
            const int kn = (t + 1) * 32;
            ry = *(const float4*)(gy + (size_t)(t + 1) * 32 * VOCAB);
            rd = *(const float4*)(gd + (size_t)(t + 1) * 32 * VOCAB);
            ra = *(const bf16x8*)(Abf + (size_t)(rbase + sr) * DMODEL + kn + skp);
            rb = *(const bf16x8*)(Bbf + (size_t)(rbase + sr) * DMODEL + kn + skp);
        }
        __syncthreads();  // LDS tile visible
        bf16x8 wy, wd;
#pragma unroll
        for (int j = 0; j < 8; ++j) {
            wy[j] = Wys[(kg * 8 + j) * 70 + wcol + cl];
            wd[j] = Wds[(kg * 8 + j) * 70 + wcol + cl];
        }
#pragma unroll
        for (int mt = 0; mt < 4; ++mt) {
            const int row = wrow + mt * 16 + cl;
            const bf16x8 a = *(const bf16x8*)&Alds[row * 32 + kg * 8];
            const bf16x8 b = *(const bf16x8*)&Blds[row * 32 + kg * 8];
            acc[mt] = __builtin_amdgcn_mfma_f32_16x16x32_bf16(a, wy, acc[mt], 0, 0, 0);
            acc[mt] = __builtin_amdgcn_mfma_f32_16x16x32_bf16(b, wd, acc[mt], 0, 0, 0);
        }
    }
    // C/D layout: col = lane&15, row-in-tile = kg*4 + r
#pragma unroll
    for (int mt = 0; mt < 4; ++mt)
#pragma unroll
        for (int r = 0; r < 4; ++r)
            out[(size_t)(rbase + wrow + mt * 16 + kg * 4 + r) * VOCAB + col] = acc[mt][r];
}

extern "C" void kernel_launch(void* const* d_in, const int* in_sizes, int n_in,
                              void* d_out, int out_size, void* d_ws, size_t ws_size,
                              hipStream_t stream) {
    const int*   ids          = (const int*)d_in[0];
    const float* emb          = (const float*)d_in[1];
    const float* attn_norm_w  = (const float*)d_in[2];
    const float* mlp_norm_w   = (const float*)d_in[3];
    const float* wqkv         = (const float*)d_in[4];
    const float* wo           = (const float*)d_in[5];
    const float* w_gate       = (const float*)d_in[6];
    const float* w_up         = (const float*)d_in[7];
    const float* w_down       = (const float*)d_in[8];
    const float* final_norm_w = (const float*)d_in[9];
    const float* rc_norm_w    = (const float*)d_in[10];
    const float* rc_w1        = (const float*)d_in[11];
    const float* rc_w2        = (const float*)d_in[12];
    const float* w_y          = (const float*)d_in[13];
    const float* w_delta      = (const float*)d_in[14];
    const float* w_halt       = (const float*)d_in[15];
    const float* b_halt       = (const float*)d_in[16];
    float* out = (float*)d_out;

    float* ws = (float*)d_ws;
    float* x       = ws + 0;         // 131072
    float* xn      = ws + 131072;    // 131072
    float* qkv     = ws + 262144;    // 393216
    float* attnout = ws + 655360;    // 131072
    float* g       = ws + 786432;    // 393216
    float* t1      = ws + 1179648;   // 524288  (refinement intermediate)
    float* states  = ws + 1703936;   // 131072
    float* states2 = ws + 1835008;   // 131072
    float* H       = ws + 1966080;   // 655360  (5 slices of 131072)
    __hip_bfloat16* Abf = (__hip_bfloat16*)(ws + 2623488);   // 131072 bf16
    __hip_bfloat16* Bbf = (__hip_bfloat16*)(ws + 2754560);   // 131072 bf16
    float* Cp      = ws + 2885632;   // 2097152 floats (split-K partials)
    // gate/up partials: 8 x 393216 floats, temporally disjoint with t1..H and
    // with Cp uses (wo's Cp consumed before gu_part; down's Cp written after
    // gu_finish) — same placement as round 6 (passing).
    float* GU      = ws + 1179648;

    // ---------- backbone ----------
    k_embed<<<NTOK, 256, 0, stream>>>(ids, emb, x);
    k_rmsnorm<<<NTOK, 256, 0, stream>>>(x, attn_norm_w, xn);
    for (int l = 0; l < NLAYER; ++l) {
        // qkv: K=512 N=1536, split 4
        k_mm_part2<<<dim3(FF / 64, 2, 4), 256, 0, stream>>>(
            xn, wqkv + (size_t)l * DMODEL * FF, Cp, DMODEL, FF, 128);
        k_qkv_finish_rope<<<NTOK, 256, 0, stream>>>(Cp, qkv);
        k_attn<<<dim3(NHEAD, NTOK), 256, 0, stream>>>(qkv, attnout);
        // wo: K=512 N=512, split 8; finish fused with rmsnorm(mlp_norm)
        k_mm_part2<<<dim3(DMODEL / 64, 2, 8), 256, 0, stream>>>(
            attnout, wo + (size_t)l * DMODEL * DMODEL, Cp, DMODEL, DMODEL, 64);
        k_finish_norm<<<NTOK, 256, 0, stream>>>(Cp, x, mlp_norm_w + l * DMODEL, x, xn, 8);
        // gate+up: one launch, z=8
        k_gu_part2<<<dim3(FF / 64, 2, 8), 256, 0, stream>>>(
            xn, w_gate + (size_t)l * DMODEL * FF, w_up + (size_t)l * DMODEL * FF, GU);
        k_finish_silumul<<<NTOK * FF / 256, 256, 0, stream>>>(GU, g);
        // down: K=1536 N=512, split 12; finish fused with next norm
        k_mm_part2<<<dim3(DMODEL / 64, 2, 12), 256, 0, stream>>>(
            g, w_down + (size_t)l * FF * DMODEL, Cp, FF, DMODEL, 128);
        const float* nw = (l == 0) ? (attn_norm_w + DMODEL) : final_norm_w;
        float* nout = (l == 0) ? xn : states;
        k_finish_norm<<<NTOK, 256, 0, stream>>>(Cp, x, nw, x, nout, 12);
    }

    // ---------- refinement steps (halt path stays f32) ----------
    k_rmsnorm<<<NTOK, 256, 0, stream>>>(states, rc_norm_w, H);
    float* scur = states;
    float* snxt = states2;
    for (int s = 0; s < NSTEPS; ++s) {
        // w1: K=512 N=2048, split 4; gelu in finish
        k_mm_part2<<<dim3(RCFF / 64, 2, 4), 256, 0, stream>>>(
            H + (size_t)s * NTOK * DMODEL, rc_w1, Cp, DMODEL, RCFF, 128);
        k_mm_finish<<<NTOK * RCFF / 256, 256, 0, stream>>>(
            Cp, nullptr, t1, NTOK * RCFF, NTOK * RCFF, 4, 1);
        // w2: K=2048 N=512, split 16; finish fused with residual + rmsnorm -> H_{s+1}
        k_mm_part2<<<dim3(DMODEL / 64, 2, 16), 256, 0, stream>>>(
            t1, rc_w2, Cp, RCFF, DMODEL, 128);
        k_finish_norm<<<NTOK, 256, 0, stream>>>(
            Cp, scur, rc_norm_w, snxt, H + (size_t)(s + 1) * NTOK * DMODEL, 16);
        float* tmp = scur; scur = snxt; snxt = tmp;
    }

    // ---------- halt + ACT + A/B in one kernel ----------
    k_haltactab<<<NTOK, 256, 0, stream>>>(H, w_halt, b_halt,
                                          out + (size_t)NTOK * VOCAB,
                                          out + (size_t)NTOK * VOCAB + NTOK,
                                          Abf, Bbf);

    // ---------- final logits (MFMA bf16, M-split, LDS-staged) ----------
    k_logits_mfma<<<dim3(VOCAB / 64, 2), 512, 0, stream>>>(Abf, Bbf, w_y, w_delta, out);
}